// Round 1
// baseline (1012.590 us; speedup 1.0000x reference)
//
#include <hip/hip_runtime.h>

#define B_ 8
#define H_ 8
#define N_ 4096
#define K_ 32
#define D_ 16
// rows = B*H*N = 262144; per-row k/v = D*K = 512 floats (2 KiB, contiguous)

__device__ __forceinline__ float4 ld4(const float* p) {
    return *reinterpret_cast<const float4*>(p);
}

__global__ __launch_bounds__(256) void pe_attn_kernel(
    const float* __restrict__ q, const float* __restrict__ kmat,
    const float* __restrict__ vmat, const float* __restrict__ xyz,
    const float* __restrict__ W1, const float* __restrict__ b1,
    const float* __restrict__ W2, const float* __restrict__ b2,
    float* __restrict__ out)
{
    const int lane = threadIdx.x & 63;
    const int wid  = threadIdx.x >> 6;
    const int row  = (blockIdx.x << 2) + wid;     // (b*H + h)*N + n
    const int n  = row & (N_ - 1);
    const int bh = row >> 12;
    const int h  = bh & (H_ - 1);
    const int b  = bh >> 3;

    __shared__ float attn_s[4][32];

    const size_t row512 = (size_t)row * (D_ * K_);
    const float* krow = kmat + row512;
    const float* vrow = vmat + row512;
    const float* qrow = q + (size_t)row * D_;

    // ---------------- energy = q.k ----------------
    // k layout within row: k[d*32 + kc]. Chunk at elem 4*lane: d=lane>>3,
    // kc0=4*(lane&7). Chunk at 256+4*lane: d=8+(lane>>3), same kc0.
    const int dg = lane >> 3;   // d-group 0..7
    const int kg = lane & 7;    // column group: columns 4*kg .. 4*kg+3

    float qa = qrow[dg];
    float qb = qrow[8 + dg];
    float4 k1 = ld4(krow + 4 * lane);
    float4 k2 = ld4(krow + 256 + 4 * lane);

    float4 e;
    e.x = fmaf(qa, k1.x, qb * k2.x);
    e.y = fmaf(qa, k1.y, qb * k2.y);
    e.z = fmaf(qa, k1.z, qb * k2.z);
    e.w = fmaf(qa, k1.w, qb * k2.w);

    // sum over the 8 d-groups (bits 3..5 of lane)
    #pragma unroll
    for (int m = 8; m <= 32; m <<= 1) {
        e.x += __shfl_xor(e.x, m);
        e.y += __shfl_xor(e.y, m);
        e.z += __shfl_xor(e.z, m);
        e.w += __shfl_xor(e.w, m);
    }

    // ---------------- + e_xyz = xyz[b,n,kc,:].W1[:,h] + b1[h] ----------------
    const float* xrow = xyz + (size_t)(b * N_ + n) * (K_ * 3) + 12 * kg;
    float4 f0 = ld4(xrow);      // kc0:{x,y,z}, kc1:{x}
    float4 f1 = ld4(xrow + 4);  // kc1:{y,z}, kc2:{x,y}
    float4 f2 = ld4(xrow + 8);  // kc2:{z}, kc3:{x,y,z}
    float w10 = W1[h], w11 = W1[H_ + h], w12 = W1[2 * H_ + h];
    float bb1 = b1[h];
    e.x += fmaf(f0.x, w10, fmaf(f0.y, w11, fmaf(f0.z, w12, bb1)));
    e.y += fmaf(f0.w, w10, fmaf(f1.x, w11, fmaf(f1.y, w12, bb1)));
    e.z += fmaf(f1.z, w10, fmaf(f1.w, w11, fmaf(f2.x, w12, bb1)));
    e.w += fmaf(f2.y, w10, fmaf(f2.z, w11, fmaf(f2.w, w12, bb1)));

    // scale = sqrt(D) = 4
    e.x *= 0.25f; e.y *= 0.25f; e.z *= 0.25f; e.w *= 0.25f;

    // ---------------- softmax over 32 columns ----------------
    float mx = fmaxf(fmaxf(e.x, e.y), fmaxf(e.z, e.w));
    #pragma unroll
    for (int m = 1; m <= 4; m <<= 1) mx = fmaxf(mx, __shfl_xor(mx, m));

    float4 p;
    p.x = __expf(e.x - mx);
    p.y = __expf(e.y - mx);
    p.z = __expf(e.z - mx);
    p.w = __expf(e.w - mx);
    float s = (p.x + p.y) + (p.z + p.w);
    #pragma unroll
    for (int m = 1; m <= 4; m <<= 1) s += __shfl_xor(s, m);
    float invs = 1.0f / s;

    if (lane < 8) {
        float4 a4 = make_float4(p.x * invs, p.y * invs, p.z * invs, p.w * invs);
        *reinterpret_cast<float4*>(&attn_s[wid][4 * kg]) = a4;
    }
    __syncthreads();

    // ---------------- output: sum_k attn[k] * (v[k,d] + v_xyz[k,d]) ----------
    // v chunk at 4*lane: k=lane>>2, d0=(lane&3)*4; chunk at 256+4*lane: k=16+(lane>>2)
    const int kq = lane >> 2;          // 0..15
    const int d0 = (lane & 3) << 2;
    float a1 = attn_s[wid][kq];
    float a2 = attn_s[wid][16 + kq];

    float4 v1 = ld4(vrow + 4 * lane);
    float4 v2 = ld4(vrow + 256 + 4 * lane);

    // reshape bijection: v_xyz[b,h,n,k,d] = xyz[b, nsrc, ksrc, :].W2[:, o] + b2[o]
    //   nsrc = (h<<9)|(n>>3); ksrc = ((n&7)<<2)|(k>>3); o = ((k&7)<<4)|d
    const int nsrc = (h << 9) | (n >> 3);
    const int kb   = (n & 7) << 2;
    const int ks1  = kb + (kq >> 3);        // k = kq
    const int ks2  = kb + 2 + (kq >> 3);    // k = 16+kq  ((16+kq)>>3 = 2+(kq>>3))
    const int o1   = ((kq & 7) << 4) | d0;  // same o for both chunks ((16+kq)&7==kq&7)

    const float* xvb = xyz + (size_t)(b * N_ + nsrc) * (K_ * 3);
    float X1 = xvb[ks1 * 3], Y1 = xvb[ks1 * 3 + 1], Z1 = xvb[ks1 * 3 + 2];
    float X2 = xvb[ks2 * 3], Y2 = xvb[ks2 * 3 + 1], Z2 = xvb[ks2 * 3 + 2];
    float4 w20 = ld4(W2 + o1);
    float4 w21 = ld4(W2 + 128 + o1);
    float4 w22 = ld4(W2 + 256 + o1);
    float4 bb2 = ld4(b2 + o1);

    float4 acc;
    {
        float vx;
        vx = fmaf(X1, w20.x, fmaf(Y1, w21.x, fmaf(Z1, w22.x, bb2.x)));
        acc.x = a1 * (v1.x + vx);
        vx = fmaf(X1, w20.y, fmaf(Y1, w21.y, fmaf(Z1, w22.y, bb2.y)));
        acc.y = a1 * (v1.y + vx);
        vx = fmaf(X1, w20.z, fmaf(Y1, w21.z, fmaf(Z1, w22.z, bb2.z)));
        acc.z = a1 * (v1.z + vx);
        vx = fmaf(X1, w20.w, fmaf(Y1, w21.w, fmaf(Z1, w22.w, bb2.w)));
        acc.w = a1 * (v1.w + vx);

        vx = fmaf(X2, w20.x, fmaf(Y2, w21.x, fmaf(Z2, w22.x, bb2.x)));
        acc.x = fmaf(a2, v2.x + vx, acc.x);
        vx = fmaf(X2, w20.y, fmaf(Y2, w21.y, fmaf(Z2, w22.y, bb2.y)));
        acc.y = fmaf(a2, v2.y + vx, acc.y);
        vx = fmaf(X2, w20.z, fmaf(Y2, w21.z, fmaf(Z2, w22.z, bb2.z)));
        acc.z = fmaf(a2, v2.z + vx, acc.z);
        vx = fmaf(X2, w20.w, fmaf(Y2, w21.w, fmaf(Z2, w22.w, bb2.w)));
        acc.w = fmaf(a2, v2.w + vx, acc.w);
    }

    // sum over k: bits 2..5 of lane (16 lanes × 2 chunks = all 32 k)
    #pragma unroll
    for (int m = 4; m <= 32; m <<= 1) {
        acc.x += __shfl_xor(acc.x, m);
        acc.y += __shfl_xor(acc.y, m);
        acc.z += __shfl_xor(acc.z, m);
        acc.w += __shfl_xor(acc.w, m);
    }

    if (lane < 4) {
        float* op = out + ((size_t)(b * N_ + n) * H_ + h) * D_ + d0;
        *reinterpret_cast<float4*>(op) = acc;
    }
}

extern "C" void kernel_launch(void* const* d_in, const int* in_sizes, int n_in,
                              void* d_out, int out_size, void* d_ws, size_t ws_size,
                              hipStream_t stream) {
    const float* q   = (const float*)d_in[0];
    const float* k   = (const float*)d_in[1];
    const float* v   = (const float*)d_in[2];
    const float* xyz = (const float*)d_in[3];
    const float* W1  = (const float*)d_in[4];
    const float* b1  = (const float*)d_in[5];
    const float* W2  = (const float*)d_in[6];
    const float* b2  = (const float*)d_in[7];
    float* out = (float*)d_out;

    dim3 grid(B_ * H_ * N_ / 4);   // 4 waves/block, 1 row/wave
    dim3 block(256);
    hipLaunchKernelGGL(pe_attn_kernel, grid, block, 0, stream,
                       q, k, v, xyz, W1, b1, W2, b2, out);
}

// Round 2
// 1008.096 us; speedup vs baseline: 1.0045x; 1.0045x over previous
//
#include <hip/hip_runtime.h>

#define B_ 8
#define H_ 8
#define N_ 4096
#define K_ 32
#define D_ 16
// rows = B*H*N = 262144; per-row k/v = D*K = 512 floats (2 KiB, contiguous)

__device__ __forceinline__ float4 ld4(const float* p) {
    return *reinterpret_cast<const float4*>(p);
}

__global__ __launch_bounds__(256) void pe_attn_kernel(
    const float* __restrict__ q, const float* __restrict__ kmat,
    const float* __restrict__ vmat, const float* __restrict__ xyz,
    const float* __restrict__ W1, const float* __restrict__ b1,
    const float* __restrict__ W2, const float* __restrict__ b2,
    float* __restrict__ out)
{
    const int lane = threadIdx.x & 63;
    const int wid  = threadIdx.x >> 6;
    const int row  = (blockIdx.x << 2) + wid;     // (b*H + h)*N + n
    const int n  = row & (N_ - 1);
    const int bh = row >> 12;
    const int h  = bh & (H_ - 1);
    const int b  = bh >> 3;

    __shared__ float attn_s[4][32];

    const size_t row512 = (size_t)row * (D_ * K_);
    const float* krow = kmat + row512;
    const float* vrow = vmat + row512;
    const float* qrow = q + (size_t)row * D_;

    const int dg = lane >> 3;   // d-group 0..7  (energy phase)
    const int kg = lane & 7;    // column group: columns 4*kg .. 4*kg+3
    const int kq = lane >> 2;   // 0..15          (output phase)
    const int d0 = (lane & 3) << 2;

    // ======== issue ALL global loads up front (single memory phase) ========
    float4 k1 = ld4(krow + 4 * lane);
    float4 k2 = ld4(krow + 256 + 4 * lane);
    float4 v1 = ld4(vrow + 4 * lane);
    float4 v2 = ld4(vrow + 256 + 4 * lane);

    float qa = qrow[dg] * 0.25f;          // fold 1/sqrt(D)=0.25 into q
    float qb = qrow[8 + dg] * 0.25f;

    const float* xrow = xyz + (size_t)(b * N_ + n) * (K_ * 3) + 12 * kg;
    float4 f0 = ld4(xrow);      // kc0:{x,y,z}, kc1:{x}
    float4 f1 = ld4(xrow + 4);  // kc1:{y,z}, kc2:{x,y}
    float4 f2 = ld4(xrow + 8);  // kc2:{z}, kc3:{x,y,z}
    float w10 = W1[h] * 0.25f, w11 = W1[H_ + h] * 0.25f, w12 = W1[2 * H_ + h] * 0.25f;
    float bb1 = b1[h] * 0.25f;

    // reshape bijection: v_xyz[b,h,n,k,d] = xyz[b, nsrc, ksrc, :].W2[:, o] + b2[o]
    //   nsrc = (h<<9)|(n>>3); ksrc = ((n&7)<<2)|(k>>3); o = ((k&7)<<4)|d
    const int nsrc = (h << 9) | (n >> 3);
    const int kb   = (n & 7) << 2;
    const int ks1  = kb + (kq >> 3);        // for k = kq
    const int ks2  = kb + 2 + (kq >> 3);    // for k = 16+kq
    const int o1   = ((kq & 7) << 4) | d0;  // same o for both chunks

    const float* xvb = xyz + (size_t)(b * N_ + nsrc) * (K_ * 3);
    float X1 = xvb[ks1 * 3], Y1 = xvb[ks1 * 3 + 1], Z1 = xvb[ks1 * 3 + 2];
    float X2 = xvb[ks2 * 3], Y2 = xvb[ks2 * 3 + 1], Z2 = xvb[ks2 * 3 + 2];
    float4 w20 = ld4(W2 + o1);
    float4 w21 = ld4(W2 + 128 + o1);
    float4 w22 = ld4(W2 + 256 + o1);
    float4 bb2 = ld4(b2 + o1);

    // ======== energy = (q.k)/4 ========
    float4 e;
    e.x = fmaf(qa, k1.x, qb * k2.x);
    e.y = fmaf(qa, k1.y, qb * k2.y);
    e.z = fmaf(qa, k1.z, qb * k2.z);
    e.w = fmaf(qa, k1.w, qb * k2.w);

    #pragma unroll
    for (int m = 8; m <= 32; m <<= 1) {   // reduce over 8 d-groups
        e.x += __shfl_xor(e.x, m);
        e.y += __shfl_xor(e.y, m);
        e.z += __shfl_xor(e.z, m);
        e.w += __shfl_xor(e.w, m);
    }

    // + e_xyz/4 = (xyz[b,n,kc,:].W1[:,h] + b1[h])/4   (scale pre-folded)
    e.x += fmaf(f0.x, w10, fmaf(f0.y, w11, fmaf(f0.z, w12, bb1)));
    e.y += fmaf(f0.w, w10, fmaf(f1.x, w11, fmaf(f1.y, w12, bb1)));
    e.z += fmaf(f1.z, w10, fmaf(f1.w, w11, fmaf(f2.x, w12, bb1)));
    e.w += fmaf(f2.y, w10, fmaf(f2.z, w11, fmaf(f2.w, w12, bb1)));

    // ======== softmax over 32 columns ========
    float mx = fmaxf(fmaxf(e.x, e.y), fmaxf(e.z, e.w));
    #pragma unroll
    for (int m = 1; m <= 4; m <<= 1) mx = fmaxf(mx, __shfl_xor(mx, m));

    float4 p;
    p.x = __expf(e.x - mx);
    p.y = __expf(e.y - mx);
    p.z = __expf(e.z - mx);
    p.w = __expf(e.w - mx);
    float s = (p.x + p.y) + (p.z + p.w);
    #pragma unroll
    for (int m = 1; m <= 4; m <<= 1) s += __shfl_xor(s, m);
    float invs = 1.0f / s;

    // wave-local LDS round-trip (attn_s[wid] touched ONLY by wave wid →
    // no __syncthreads needed; wave_barrier pins compiler scheduling)
    if (lane < 8) {
        float4 a4 = make_float4(p.x * invs, p.y * invs, p.z * invs, p.w * invs);
        *reinterpret_cast<float4*>(&attn_s[wid][4 * kg]) = a4;
    }
    __builtin_amdgcn_wave_barrier();
    float a1 = attn_s[wid][kq];
    float a2 = attn_s[wid][16 + kq];
    __builtin_amdgcn_wave_barrier();

    // ======== output: sum_k attn[k] * (v[k,d] + v_xyz[k,d]) ========
    float4 acc;
    {
        float vx;
        vx = fmaf(X1, w20.x, fmaf(Y1, w21.x, fmaf(Z1, w22.x, bb2.x)));
        acc.x = a1 * (v1.x + vx);
        vx = fmaf(X1, w20.y, fmaf(Y1, w21.y, fmaf(Z1, w22.y, bb2.y)));
        acc.y = a1 * (v1.y + vx);
        vx = fmaf(X1, w20.z, fmaf(Y1, w21.z, fmaf(Z1, w22.z, bb2.z)));
        acc.z = a1 * (v1.z + vx);
        vx = fmaf(X1, w20.w, fmaf(Y1, w21.w, fmaf(Z1, w22.w, bb2.w)));
        acc.w = a1 * (v1.w + vx);

        vx = fmaf(X2, w20.x, fmaf(Y2, w21.x, fmaf(Z2, w22.x, bb2.x)));
        acc.x = fmaf(a2, v2.x + vx, acc.x);
        vx = fmaf(X2, w20.y, fmaf(Y2, w21.y, fmaf(Z2, w22.y, bb2.y)));
        acc.y = fmaf(a2, v2.y + vx, acc.y);
        vx = fmaf(X2, w20.z, fmaf(Y2, w21.z, fmaf(Z2, w22.z, bb2.z)));
        acc.z = fmaf(a2, v2.z + vx, acc.z);
        vx = fmaf(X2, w20.w, fmaf(Y2, w21.w, fmaf(Z2, w22.w, bb2.w)));
        acc.w = fmaf(a2, v2.w + vx, acc.w);
    }

    // sum over k: bits 2..5 of lane (16 lanes × 2 chunks = all 32 k)
    #pragma unroll
    for (int m = 4; m <= 32; m <<= 1) {
        acc.x += __shfl_xor(acc.x, m);
        acc.y += __shfl_xor(acc.y, m);
        acc.z += __shfl_xor(acc.z, m);
        acc.w += __shfl_xor(acc.w, m);
    }

    if (lane < 4) {
        float* op = out + ((size_t)(b * N_ + n) * H_ + h) * D_ + d0;
        *reinterpret_cast<float4*>(op) = acc;
    }
}

extern "C" void kernel_launch(void* const* d_in, const int* in_sizes, int n_in,
                              void* d_out, int out_size, void* d_ws, size_t ws_size,
                              hipStream_t stream) {
    const float* q   = (const float*)d_in[0];
    const float* k   = (const float*)d_in[1];
    const float* v   = (const float*)d_in[2];
    const float* xyz = (const float*)d_in[3];
    const float* W1  = (const float*)d_in[4];
    const float* b1  = (const float*)d_in[5];
    const float* W2  = (const float*)d_in[6];
    const float* b2  = (const float*)d_in[7];
    float* out = (float*)d_out;

    dim3 grid(B_ * H_ * N_ / 4);   // 4 waves/block, 1 row/wave
    dim3 block(256);
    hipLaunchKernelGGL(pe_attn_kernel, grid, block, 0, stream,
                       q, k, v, xyz, W1, b1, W2, b2, out);
}